// Round 11
// baseline (4220.878 us; speedup 1.0000x reference)
//
#include <hip/hip_runtime.h>

// ---------------------------------------------------------------------------
// Problem: B=128, T=256, N=512, M=512.
// softmax over a constant row == uniform 1/N => attention arm is dead code.
// Op is an LSTM with inputs scaled by 1/512.
//   xg[b,t,j] = sum_n x[b,t,n]/512 * w_ih[j,n] + b_ih[j] + b_hh[j]   (GEMM)
//   per step:  gates = xg[:,t,:] + h @ w_hh^T ; LSTM cell; out = h
//
// R9: R2-proven protocol (drain -> fetch_add publish -> atomic_load poll ->
// load data), restructured to cut publishers per chain 16 -> 4.
// SESSION RULE (R3/R4/R5/R8 all aborted, R2/R7 passed): never spin on the
// DATA location with sc0sc1 loads; poll only via __hip_atomic_load on a
// flag/counter, then read data.
//   - chain = 16 batches (8 chains); wg = 8 waves (512 thr, full CU at
//     256 VGPR) covering 16b x 128m; 4 wgs per chain.
//   - publish: one fetch_add per wg per step (4 RMWs/chain vs R2's 16);
//     poll: tid0 __hip_atomic_load until ctr >= 4*t; __syncthreads.
//   - all load/wait/store micro-patterns byte-identical to R2/R7.
// ---------------------------------------------------------------------------

typedef __attribute__((ext_vector_type(8))) __bf16 bf16x8;
typedef __attribute__((ext_vector_type(8))) unsigned short u16x8;
typedef __attribute__((ext_vector_type(4))) float f32x4;
typedef unsigned short ushort_t;

__device__ __forceinline__ unsigned short f2b(float f) {
  unsigned u = __builtin_bit_cast(unsigned, f);
  unsigned r = (u + 0x7FFFu + ((u >> 16) & 1u)) >> 16;
  return (unsigned short)r;
}
__device__ __forceinline__ float b2f(unsigned short s) {
  unsigned u = ((unsigned)s) << 16;
  return __builtin_bit_cast(float, u);
}
__device__ __forceinline__ float sigm(float x) { return 1.0f / (1.0f + __expf(-x)); }
__device__ __forceinline__ float tanh_f(float x) { return 1.0f - 2.0f / (__expf(2.0f * x) + 1.0f); }

#define VMCNT(n) asm volatile("s_waitcnt vmcnt(" #n ")" ::: "memory")

// Coherent (Infinity-Cache-level) accesses: sc0 sc1 bypass L1 and the
// non-coherent per-XCD L2 on both sides (proven in R2/R7).
__device__ __forceinline__ void hload16(f32x4* dst, const ushort_t* p) {
  asm volatile("global_load_dwordx4 %0, %1, off sc0 sc1"
               : "=v"(*dst) : "v"(p) : "memory");
}
__device__ __forceinline__ void hstore2(ushort_t* p, unsigned v) {
  asm volatile("global_store_short %0, %1, off sc0 sc1"
               :: "v"(p), "v"(v) : "memory");
}
__device__ __forceinline__ void xload_f32(unsigned* dst, const float* p) {
  asm volatile("global_load_dword %0, %1, off" : "=v"(*dst) : "v"(p) : "memory");
}
__device__ __forceinline__ void xload_bf(unsigned* dst, const ushort_t* p) {
  asm volatile("global_load_ushort %0, %1, off" : "=v"(*dst) : "v"(p) : "memory");
}

// ---------------------------------------------------------------------------
// Kernel 1: convert inputs -> bf16 (scaled 1/512), w_ih -> bf16, bias sum.
// ---------------------------------------------------------------------------
__global__ __launch_bounds__(256) void convert_kernel(
    const float* __restrict__ inp, const float* __restrict__ wih,
    const float* __restrict__ bih, const float* __restrict__ bhh,
    ushort_t* __restrict__ X, ushort_t* __restrict__ W, float* __restrict__ bias)
{
  int tid = blockIdx.x * 256 + threadIdx.x;
  int stride = gridDim.x * 256;
  const float s = 1.0f / 512.0f;
  for (int i = tid; i < (16777216 / 4); i += stride) {
    float4 v = reinterpret_cast<const float4*>(inp)[i];
    ushort4 o; o.x = f2b(v.x * s); o.y = f2b(v.y * s); o.z = f2b(v.z * s); o.w = f2b(v.w * s);
    reinterpret_cast<ushort4*>(X)[i] = o;
  }
  for (int i = tid; i < (1048576 / 4); i += stride) {
    float4 v = reinterpret_cast<const float4*>(wih)[i];
    ushort4 o; o.x = f2b(v.x); o.y = f2b(v.y); o.z = f2b(v.z); o.w = f2b(v.w);
    reinterpret_cast<ushort4*>(W)[i] = o;
  }
  for (int i = tid; i < 2048; i += stride) bias[i] = bih[i] + bhh[i];
}

// ---------------------------------------------------------------------------
// Kernel 2: xg GEMM. C[32768,2048] = X[32768,512](bf16) @ W[2048,512]^T + bias.
// ---------------------------------------------------------------------------
template<bool XGBF>
__global__ __launch_bounds__(256) void gemm_xg_kernel(
    const ushort_t* __restrict__ X, const ushort_t* __restrict__ W,
    const float* __restrict__ bias, void* __restrict__ xg)
{
  __shared__ bf16x8 AsV[1024];
  __shared__ bf16x8 BsV[1024];
  ushort_t* As = (ushort_t*)AsV;
  ushort_t* Bs = (ushort_t*)BsV;

  int tid = threadIdx.x;
  int lane = tid & 63;
  int wv = tid >> 6;
  int wr = wv >> 1, wc = wv & 1;
  int ll = lane & 15;
  int kg = lane >> 4;
  int bm = blockIdx.x & 255;
  int bn = blockIdx.x >> 8;

  f32x4 acc[4][4];
#pragma unroll
  for (int i = 0; i < 4; ++i)
#pragma unroll
    for (int j = 0; j < 4; ++j) acc[i][j] = (f32x4){0.f, 0.f, 0.f, 0.f};

  for (int kt = 0; kt < 8; ++kt) {
#pragma unroll
    for (int it = 0; it < 4; ++it) {
      int i = it * 256 + tid;
      int row = i >> 3, ch = i & 7;
      int de = row * 64 + ((ch ^ (row & 7)) << 3);
      *reinterpret_cast<bf16x8*>(As + de) =
          *reinterpret_cast<const bf16x8*>(X + (size_t)(bm * 128 + row) * 512 + kt * 64 + ch * 8);
      *reinterpret_cast<bf16x8*>(Bs + de) =
          *reinterpret_cast<const bf16x8*>(W + (size_t)(bn * 128 + row) * 512 + kt * 64 + ch * 8);
    }
    __syncthreads();
#pragma unroll
    for (int kc = 0; kc < 2; ++kc) {
      int kch = kc * 4 + kg;
      bf16x8 a[4], b[4];
#pragma unroll
      for (int fi = 0; fi < 4; ++fi) {
        int row = wr * 64 + fi * 16 + ll;
        a[fi] = *reinterpret_cast<const bf16x8*>(As + row * 64 + ((kch ^ (row & 7)) << 3));
      }
#pragma unroll
      for (int fj = 0; fj < 4; ++fj) {
        int row = wc * 64 + fj * 16 + ll;
        b[fj] = *reinterpret_cast<const bf16x8*>(Bs + row * 64 + ((kch ^ (row & 7)) << 3));
      }
#pragma unroll
      for (int fi = 0; fi < 4; ++fi)
#pragma unroll
        for (int fj = 0; fj < 4; ++fj)
          acc[fi][fj] = __builtin_amdgcn_mfma_f32_16x16x32_bf16(a[fi], b[fj], acc[fi][fj], 0, 0, 0);
    }
    __syncthreads();
  }
#pragma unroll
  for (int fj = 0; fj < 4; ++fj) {
    int colj = bn * 128 + wc * 64 + fj * 16 + ll;
    float bv = bias[colj];
#pragma unroll
    for (int fi = 0; fi < 4; ++fi)
#pragma unroll
      for (int r = 0; r < 4; ++r) {
        int rowi = bm * 128 + wr * 64 + fi * 16 + kg * 4 + r;
        float v = acc[fi][fj][r] + bv;
        if constexpr (XGBF) ((ushort_t*)xg)[(size_t)rowi * 2048 + colj] = f2b(v);
        else                ((float*)xg)[(size_t)rowi * 2048 + colj] = v;
      }
  }
}

// ---------------------------------------------------------------------------
// Kernel 3: persistent LSTM recurrence, 4-publisher chains.
// 32 wgs x 512 thr (8 waves, full CU). Chain gb (16 batches) is served by
// 4 wgs; each wg covers 16b x 128m (waves: m sub-tiles). w_hh in VGPRs.
// Step: [tid0 poll ctr >= 4t; barrier] -> h+xg loads -> counted-vmcnt MFMA
// -> gates -> sc0sc1 h stores -> VMCNT(0) -> barrier -> tid0 fetch_add ->
// out stores. All micro-patterns verbatim R2/R7.
// ---------------------------------------------------------------------------
template<bool XGBF>
__global__ __launch_bounds__(512, 2) void lstm_rec_kernel(
    const float* __restrict__ whh, const void* __restrict__ xg,
    ushort_t* __restrict__ hbuf /*[2][128][512] bf16*/, float* __restrict__ out,
    unsigned* __restrict__ ctrs /*8 counters, 128B apart*/)
{
  int tid = threadIdx.x;
  int lane = tid & 63;
  int wv = tid >> 6;             // 0..7: m sub-tile within wg
  int gb = blockIdx.x >> 2;      // chain 0..7
  int wgm = blockIdx.x & 3;      // wg's m quarter 0..3
  int ll = lane & 15, kg = lane >> 4;
  int b0 = gb * 16;
  int m0 = wgm * 128 + wv * 16;
  unsigned* ctr = ctrs + gb * 32;  // 128 B apart per chain

  // preload w_hh fragments -> registers (fp32 read once, cvt to bf16)
  bf16x8 bfr[4][16];
#pragma unroll
  for (int g = 0; g < 4; ++g) {
    const float* wrow = whh + (size_t)(g * 512 + m0 + ll) * 512;
#pragma unroll
    for (int ks = 0; ks < 16; ++ks) {
      const float4* wp = reinterpret_cast<const float4*>(wrow + ks * 32 + kg * 8);
      float4 lo = wp[0], hi = wp[1];
      u16x8 tbits;
      tbits[0] = f2b(lo.x); tbits[1] = f2b(lo.y); tbits[2] = f2b(lo.z); tbits[3] = f2b(lo.w);
      tbits[4] = f2b(hi.x); tbits[5] = f2b(hi.y); tbits[6] = f2b(hi.z); tbits[7] = f2b(hi.w);
      bfr[g][ks] = __builtin_bit_cast(bf16x8, tbits);
    }
  }

  float c[4] = {0.f, 0.f, 0.f, 0.f};
  size_t lanebase = (size_t)(b0 + kg * 4) * 524288 + m0 + ll;  // xg elements

  for (int t = 0; t < 256; ++t) {
    // ---- poll: h(t) ready when all 4 wgs of this chain published t-1 ----
    if (tid == 0) {
      unsigned tgt = 4u * (unsigned)t;
      unsigned guard = 0;
      while (__hip_atomic_load(ctr, __ATOMIC_RELAXED, __HIP_MEMORY_SCOPE_AGENT) < tgt) {
        if (++guard > (1u << 15)) break;   // valve: terminate, don't hang
        __builtin_amdgcn_s_sleep(1);
      }
    }
    __syncthreads();

    // ---- issue 16 h loads (coherent) + 16 xg loads (plain, in-step) ----
    const ushort_t* hrow = hbuf + (size_t)(t & 1) * 65536 + (size_t)(b0 + ll) * 512 + kg * 8;
    f32x4 hraw[16];
#pragma unroll
    for (int ks = 0; ks < 16; ++ks) hload16(&hraw[ks], hrow + ks * 32);

    unsigned xv[16];
#pragma unroll
    for (int g = 0; g < 4; ++g)
#pragma unroll
      for (int r = 0; r < 4; ++r) {
        size_t off = lanebase + (size_t)r * 524288 + g * 512 + (size_t)t * 2048;
        if constexpr (XGBF) xload_bf(&xv[g * 4 + r], (const ushort_t*)xg + off);
        else                xload_f32(&xv[g * 4 + r], (const float*)xg + off);
      }

    // ---- MFMA as h loads land. Outstanding (oldest->newest): [<=5 stale
    // (4 out stores + tid0's publish RMW)][16 h][16 xg]. VMCNT(24) ->
    // h[0..7] done; VMCNT(16) -> all h done (in-order retirement). ----
    f32x4 acc[4];
#pragma unroll
    for (int g = 0; g < 4; ++g) acc[g] = (f32x4){0.f, 0.f, 0.f, 0.f};
    VMCNT(24);
    __builtin_amdgcn_sched_barrier(0);
#pragma unroll
    for (int ks = 0; ks < 8; ++ks) {
      bf16x8 a = __builtin_bit_cast(bf16x8, hraw[ks]);
#pragma unroll
      for (int g = 0; g < 4; ++g)
        acc[g] = __builtin_amdgcn_mfma_f32_16x16x32_bf16(a, bfr[g][ks], acc[g], 0, 0, 0);
    }
    VMCNT(16);
    __builtin_amdgcn_sched_barrier(0);
#pragma unroll
    for (int ks = 8; ks < 16; ++ks) {
      bf16x8 a = __builtin_bit_cast(bf16x8, hraw[ks]);
#pragma unroll
      for (int g = 0; g < 4; ++g)
        acc[g] = __builtin_amdgcn_mfma_f32_16x16x32_bf16(a, bfr[g][ks], acc[g], 0, 0, 0);
    }
    VMCNT(0);                              // xg landed
    __builtin_amdgcn_sched_barrier(0);

    // ---- gates + state update; coherent per-ushort h stores ----
    ushort_t* hw = hbuf + (size_t)((t + 1) & 1) * 65536;
    float hv[4];
#pragma unroll
    for (int r = 0; r < 4; ++r) {
      float x0, x1, x2, x3;
      if constexpr (XGBF) {
        x0 = b2f((ushort_t)xv[0 * 4 + r]); x1 = b2f((ushort_t)xv[1 * 4 + r]);
        x2 = b2f((ushort_t)xv[2 * 4 + r]); x3 = b2f((ushort_t)xv[3 * 4 + r]);
      } else {
        x0 = __builtin_bit_cast(float, xv[0 * 4 + r]); x1 = __builtin_bit_cast(float, xv[1 * 4 + r]);
        x2 = __builtin_bit_cast(float, xv[2 * 4 + r]); x3 = __builtin_bit_cast(float, xv[3 * 4 + r]);
      }
      float ig = sigm(acc[0][r] + x0);
      float fg = sigm(acc[1][r] + x1);
      float gg = tanh_f(acc[2][r] + x2);
      float og = sigm(acc[3][r] + x3);
      c[r] = fg * c[r] + ig * gg;
      hv[r] = og * tanh_f(c[r]);
      hstore2(hw + (size_t)(b0 + kg * 4 + r) * 512 + m0 + ll, (unsigned)f2b(hv[r]));
    }

    // ---- drain h stores; publish (fire-and-forget); out stores fly ----
    VMCNT(0);
    __builtin_amdgcn_sched_barrier(0);
    __syncthreads();                       // all 8 waves drained
    if (tid == 0)
      __hip_atomic_fetch_add(ctr, 1u, __ATOMIC_RELAXED, __HIP_MEMORY_SCOPE_AGENT);
#pragma unroll
    for (int r = 0; r < 4; ++r)
      __builtin_nontemporal_store(hv[r], out + ((size_t)(b0 + kg * 4 + r) * 256 + t) * 512 + m0 + ll);
  }
}

// ---------------------------------------------------------------------------
extern "C" void kernel_launch(void* const* d_in, const int* in_sizes, int n_in,
                              void* d_out, int out_size, void* d_ws, size_t ws_size,
                              hipStream_t stream)
{
  const float* inputs = (const float*)d_in[0];
  // d_in[1..3] = W_e_w, W_e_b, U_e_w : dead (softmax of constant row)
  const float* w_ih = (const float*)d_in[4];
  const float* w_hh = (const float*)d_in[5];
  const float* b_ih = (const float*)d_in[6];
  const float* b_hh = (const float*)d_in[7];
  float* out = (float*)d_out;
  char* ws = (char*)d_ws;

  const size_t xg_f32_bytes = (size_t)32768 * 2048 * 4;  // 268.4 MB
  const size_t xg_bf_bytes  = (size_t)32768 * 2048 * 2;  // 134.2 MB
  const size_t xbytes = (size_t)16777216 * 2;            // X bf16
  const size_t wbytes = (size_t)1048576 * 2;             // w_ih bf16
  const size_t biasb  = 2048 * 4;
  const size_t hbytes = (size_t)2 * 128 * 512 * 2;       // h double buffer
  const size_t ctrb   = 1024;                            // 8 counters, 128B apart
  const size_t tail = xbytes + wbytes + biasb + hbytes + ctrb + 1024;

  bool f32p = ws_size >= xg_f32_bytes + tail;            // adaptive xg precision
  size_t xgb  = f32p ? xg_f32_bytes : xg_bf_bytes;
  size_t oX   = xgb;
  size_t oW   = oX + xbytes;
  size_t oB   = oW + wbytes;
  size_t oH   = (oB + biasb + 255) & ~(size_t)255;
  size_t oC   = oH + hbytes;

  hipMemsetAsync(ws + oH, 0, hbytes + ctrb, stream);     // zero h0 + counters

  convert_kernel<<<2048, 256, 0, stream>>>(inputs, w_ih, b_ih, b_hh,
      (ushort_t*)(ws + oX), (ushort_t*)(ws + oW), (float*)(ws + oB));

  if (f32p) {
    gemm_xg_kernel<false><<<4096, 256, 0, stream>>>(
        (const ushort_t*)(ws + oX), (const ushort_t*)(ws + oW), (const float*)(ws + oB), ws);
    lstm_rec_kernel<false><<<32, 512, 0, stream>>>(
        w_hh, ws, (ushort_t*)(ws + oH), out, (unsigned*)(ws + oC));
  } else {
    gemm_xg_kernel<true><<<4096, 256, 0, stream>>>(
        (const ushort_t*)(ws + oX), (const ushort_t*)(ws + oW), (const float*)(ws + oB), ws);
    lstm_rec_kernel<true><<<32, 512, 0, stream>>>(
        w_hh, ws, (ushort_t*)(ws + oH), out, (unsigned*)(ws + oC));
  }
  (void)in_sizes; (void)n_in; (void)out_size;
}

// Round 12
// 1462.834 us; speedup vs baseline: 2.8854x; 2.8854x over previous
//
#include <hip/hip_runtime.h>

// ---------------------------------------------------------------------------
// Problem: B=128, T=256, N=512, M=512.
// softmax over a constant row == uniform 1/N => attention arm is dead code.
// Op is an LSTM with inputs scaled by 1/512.
//   xg[b,t,j] = sum_n x[b,t,n]/512 * w_ih[j,n] + b_ih[j] + b_hh[j]   (GEMM)
//   per step:  gates = xg[:,t,:] + h @ w_hh^T ; LSTM cell; out = h
//
// R10: R2's passing kernel BODY byte-for-byte (4 waves / 256 thr /
// __launch_bounds__(256,1) -> proven 256 VGPRs, no spill; R9's 8-wave wg
// spilled w_hh at VGPR_Count=128). Single change: the per-step sync.
//   R2: 16 serialized fetch_add RMWs on one IF line + tid0 poll
//       (~8-11k cy of the 11.6k cy step).
//   R10: per-wg flag STORE (no RMW serialization; parallel propagation)
//        + tid<16 parallel atomic_load poll. Both primitives proven.
// Session rules honored: no polling on data locations; no asm-load register
// pending across a step boundary. Valve 2^15 => failures terminate visibly.
// ---------------------------------------------------------------------------

typedef __attribute__((ext_vector_type(8))) __bf16 bf16x8;
typedef __attribute__((ext_vector_type(8))) unsigned short u16x8;
typedef __attribute__((ext_vector_type(4))) float f32x4;
typedef unsigned short ushort_t;

__device__ __forceinline__ unsigned short f2b(float f) {
  unsigned u = __builtin_bit_cast(unsigned, f);
  unsigned r = (u + 0x7FFFu + ((u >> 16) & 1u)) >> 16;
  return (unsigned short)r;
}
__device__ __forceinline__ float b2f(unsigned short s) {
  unsigned u = ((unsigned)s) << 16;
  return __builtin_bit_cast(float, u);
}
__device__ __forceinline__ float sigm(float x) { return 1.0f / (1.0f + __expf(-x)); }
__device__ __forceinline__ float tanh_f(float x) { return 1.0f - 2.0f / (__expf(2.0f * x) + 1.0f); }

#define VMCNT(n) asm volatile("s_waitcnt vmcnt(" #n ")" ::: "memory")

// Coherent (Infinity-Cache-level) accesses: sc0 sc1 bypass L1 and the
// non-coherent per-XCD L2 on both sides (proven R2/R7/R9).
__device__ __forceinline__ void hload16(f32x4* dst, const ushort_t* p) {
  asm volatile("global_load_dwordx4 %0, %1, off sc0 sc1"
               : "=v"(*dst) : "v"(p) : "memory");
}
__device__ __forceinline__ void hstore2(ushort_t* p, unsigned v) {
  asm volatile("global_store_short %0, %1, off sc0 sc1"
               :: "v"(p), "v"(v) : "memory");
}
__device__ __forceinline__ void xload_f32(unsigned* dst, const float* p) {
  asm volatile("global_load_dword %0, %1, off" : "=v"(*dst) : "v"(p) : "memory");
}
__device__ __forceinline__ void xload_bf(unsigned* dst, const ushort_t* p) {
  asm volatile("global_load_ushort %0, %1, off" : "=v"(*dst) : "v"(p) : "memory");
}

// ---------------------------------------------------------------------------
// Kernel 1: convert inputs -> bf16 (scaled 1/512), w_ih -> bf16, bias sum.
// ---------------------------------------------------------------------------
__global__ __launch_bounds__(256) void convert_kernel(
    const float* __restrict__ inp, const float* __restrict__ wih,
    const float* __restrict__ bih, const float* __restrict__ bhh,
    ushort_t* __restrict__ X, ushort_t* __restrict__ W, float* __restrict__ bias)
{
  int tid = blockIdx.x * 256 + threadIdx.x;
  int stride = gridDim.x * 256;
  const float s = 1.0f / 512.0f;
  for (int i = tid; i < (16777216 / 4); i += stride) {
    float4 v = reinterpret_cast<const float4*>(inp)[i];
    ushort4 o; o.x = f2b(v.x * s); o.y = f2b(v.y * s); o.z = f2b(v.z * s); o.w = f2b(v.w * s);
    reinterpret_cast<ushort4*>(X)[i] = o;
  }
  for (int i = tid; i < (1048576 / 4); i += stride) {
    float4 v = reinterpret_cast<const float4*>(wih)[i];
    ushort4 o; o.x = f2b(v.x); o.y = f2b(v.y); o.z = f2b(v.z); o.w = f2b(v.w);
    reinterpret_cast<ushort4*>(W)[i] = o;
  }
  for (int i = tid; i < 2048; i += stride) bias[i] = bih[i] + bhh[i];
}

// ---------------------------------------------------------------------------
// Kernel 2: xg GEMM. C[32768,2048] = X[32768,512](bf16) @ W[2048,512]^T + bias.
// ---------------------------------------------------------------------------
template<bool XGBF>
__global__ __launch_bounds__(256) void gemm_xg_kernel(
    const ushort_t* __restrict__ X, const ushort_t* __restrict__ W,
    const float* __restrict__ bias, void* __restrict__ xg)
{
  __shared__ bf16x8 AsV[1024];
  __shared__ bf16x8 BsV[1024];
  ushort_t* As = (ushort_t*)AsV;
  ushort_t* Bs = (ushort_t*)BsV;

  int tid = threadIdx.x;
  int lane = tid & 63;
  int wv = tid >> 6;
  int wr = wv >> 1, wc = wv & 1;
  int ll = lane & 15;
  int kg = lane >> 4;
  int bm = blockIdx.x & 255;
  int bn = blockIdx.x >> 8;

  f32x4 acc[4][4];
#pragma unroll
  for (int i = 0; i < 4; ++i)
#pragma unroll
    for (int j = 0; j < 4; ++j) acc[i][j] = (f32x4){0.f, 0.f, 0.f, 0.f};

  for (int kt = 0; kt < 8; ++kt) {
#pragma unroll
    for (int it = 0; it < 4; ++it) {
      int i = it * 256 + tid;
      int row = i >> 3, ch = i & 7;
      int de = row * 64 + ((ch ^ (row & 7)) << 3);
      *reinterpret_cast<bf16x8*>(As + de) =
          *reinterpret_cast<const bf16x8*>(X + (size_t)(bm * 128 + row) * 512 + kt * 64 + ch * 8);
      *reinterpret_cast<bf16x8*>(Bs + de) =
          *reinterpret_cast<const bf16x8*>(W + (size_t)(bn * 128 + row) * 512 + kt * 64 + ch * 8);
    }
    __syncthreads();
#pragma unroll
    for (int kc = 0; kc < 2; ++kc) {
      int kch = kc * 4 + kg;
      bf16x8 a[4], b[4];
#pragma unroll
      for (int fi = 0; fi < 4; ++fi) {
        int row = wr * 64 + fi * 16 + ll;
        a[fi] = *reinterpret_cast<const bf16x8*>(As + row * 64 + ((kch ^ (row & 7)) << 3));
      }
#pragma unroll
      for (int fj = 0; fj < 4; ++fj) {
        int row = wc * 64 + fj * 16 + ll;
        b[fj] = *reinterpret_cast<const bf16x8*>(Bs + row * 64 + ((kch ^ (row & 7)) << 3));
      }
#pragma unroll
      for (int fi = 0; fi < 4; ++fi)
#pragma unroll
        for (int fj = 0; fj < 4; ++fj)
          acc[fi][fj] = __builtin_amdgcn_mfma_f32_16x16x32_bf16(a[fi], b[fj], acc[fi][fj], 0, 0, 0);
    }
    __syncthreads();
  }
#pragma unroll
  for (int fj = 0; fj < 4; ++fj) {
    int colj = bn * 128 + wc * 64 + fj * 16 + ll;
    float bv = bias[colj];
#pragma unroll
    for (int fi = 0; fi < 4; ++fi)
#pragma unroll
      for (int r = 0; r < 4; ++r) {
        int rowi = bm * 128 + wr * 64 + fi * 16 + kg * 4 + r;
        float v = acc[fi][fj][r] + bv;
        if constexpr (XGBF) ((ushort_t*)xg)[(size_t)rowi * 2048 + colj] = f2b(v);
        else                ((float*)xg)[(size_t)rowi * 2048 + colj] = v;
      }
  }
}

// ---------------------------------------------------------------------------
// Kernel 3: persistent LSTM recurrence (R2 body; flag-store barrier).
// 64 wgs = 4 batch-groups (32 b) x 16 m-groups; 4 waves; w_hh in VGPRs.
// ---------------------------------------------------------------------------
template<bool XGBF>
__global__ __launch_bounds__(256, 1) void lstm_rec_kernel(
    const float* __restrict__ whh, const void* __restrict__ xg,
    ushort_t* __restrict__ hbuf /*[2][128][512] bf16*/, float* __restrict__ out,
    unsigned* __restrict__ flags /*[4][16]*/)
{
  int tid = threadIdx.x;
  int lane = tid & 63;
  int wv = tid >> 6;
  int wvb = wv >> 1, wvm = wv & 1;
  int gb = blockIdx.x >> 4;      // batch group 0..3
  int gm = blockIdx.x & 15;      // m group 0..15
  int ll = lane & 15, kg = lane >> 4;
  int b0 = gb * 32 + wvb * 16;
  int m0 = gm * 32 + wvm * 16;

  // preload w_hh fragments -> registers (fp32 read once, cvt to bf16)
  bf16x8 bfr[4][16];
#pragma unroll
  for (int g = 0; g < 4; ++g) {
    const float* wrow = whh + (size_t)(g * 512 + m0 + ll) * 512;
#pragma unroll
    for (int ks = 0; ks < 16; ++ks) {
      const float4* wp = reinterpret_cast<const float4*>(wrow + ks * 32 + kg * 8);
      float4 lo = wp[0], hi = wp[1];
      u16x8 tbits;
      tbits[0] = f2b(lo.x); tbits[1] = f2b(lo.y); tbits[2] = f2b(lo.z); tbits[3] = f2b(lo.w);
      tbits[4] = f2b(hi.x); tbits[5] = f2b(hi.y); tbits[6] = f2b(hi.z); tbits[7] = f2b(hi.w);
      bfr[g][ks] = __builtin_bit_cast(bf16x8, tbits);
    }
  }

  float c[4] = {0.f, 0.f, 0.f, 0.f};
  size_t lanebase = (size_t)(b0 + kg * 4) * 524288 + m0 + ll;  // xg elements
  unsigned* gflags = flags + gb * 16;

  for (int t = 0; t < 256; ++t) {
    // ---- issue 16 h loads (coherent) + 16 xg loads (plain, in-step) ----
    const ushort_t* hrow = hbuf + (size_t)(t & 1) * 65536 + (size_t)(b0 + ll) * 512 + kg * 8;
    f32x4 hraw[16];
#pragma unroll
    for (int ks = 0; ks < 16; ++ks) hload16(&hraw[ks], hrow + ks * 32);

    unsigned xv[16];
#pragma unroll
    for (int g = 0; g < 4; ++g)
#pragma unroll
      for (int r = 0; r < 4; ++r) {
        size_t off = lanebase + (size_t)r * 524288 + g * 512 + (size_t)t * 2048;
        if constexpr (XGBF) xload_bf(&xv[g * 4 + r], (const ushort_t*)xg + off);
        else                xload_f32(&xv[g * 4 + r], (const float*)xg + off);
      }

    // ---- MFMA as h loads land. Outstanding (oldest->newest): [<=5 stale
    // (4 out stores + 1 flag store on tid0's wave)][16 h][16 xg].
    // VMCNT(24) -> h[0..7] done; VMCNT(16) -> all h (in-order retirement) ----
    f32x4 acc[4];
#pragma unroll
    for (int g = 0; g < 4; ++g) acc[g] = (f32x4){0.f, 0.f, 0.f, 0.f};
    VMCNT(24);
    __builtin_amdgcn_sched_barrier(0);
#pragma unroll
    for (int ks = 0; ks < 8; ++ks) {
      bf16x8 a = __builtin_bit_cast(bf16x8, hraw[ks]);
#pragma unroll
      for (int g = 0; g < 4; ++g)
        acc[g] = __builtin_amdgcn_mfma_f32_16x16x32_bf16(a, bfr[g][ks], acc[g], 0, 0, 0);
    }
    VMCNT(16);
    __builtin_amdgcn_sched_barrier(0);
#pragma unroll
    for (int ks = 8; ks < 16; ++ks) {
      bf16x8 a = __builtin_bit_cast(bf16x8, hraw[ks]);
#pragma unroll
      for (int g = 0; g < 4; ++g)
        acc[g] = __builtin_amdgcn_mfma_f32_16x16x32_bf16(a, bfr[g][ks], acc[g], 0, 0, 0);
    }
    VMCNT(0);                              // xg landed
    __builtin_amdgcn_sched_barrier(0);

    // ---- gates + state update; coherent per-ushort h stores ----
    ushort_t* hw = hbuf + (size_t)((t + 1) & 1) * 65536;
    float hv[4];
#pragma unroll
    for (int r = 0; r < 4; ++r) {
      float x0, x1, x2, x3;
      if constexpr (XGBF) {
        x0 = b2f((ushort_t)xv[0 * 4 + r]); x1 = b2f((ushort_t)xv[1 * 4 + r]);
        x2 = b2f((ushort_t)xv[2 * 4 + r]); x3 = b2f((ushort_t)xv[3 * 4 + r]);
      } else {
        x0 = __builtin_bit_cast(float, xv[0 * 4 + r]); x1 = __builtin_bit_cast(float, xv[1 * 4 + r]);
        x2 = __builtin_bit_cast(float, xv[2 * 4 + r]); x3 = __builtin_bit_cast(float, xv[3 * 4 + r]);
      }
      float ig = sigm(acc[0][r] + x0);
      float fg = sigm(acc[1][r] + x1);
      float gg = tanh_f(acc[2][r] + x2);
      float og = sigm(acc[3][r] + x3);
      c[r] = fg * c[r] + ig * gg;
      hv[r] = og * tanh_f(c[r]);
      hstore2(hw + (size_t)(b0 + kg * 4 + r) * 512 + m0 + ll, (unsigned)f2b(hv[r]));
    }

    // ---- drain h stores; flag-store barrier (parallel publish + poll) ----
    VMCNT(0);
    __builtin_amdgcn_sched_barrier(0);
    if (t < 255) {
      __builtin_amdgcn_s_barrier();        // all 4 waves drained their h stores
      if (tid == 0)                        // publish: plain store, no RMW
        __hip_atomic_store(&gflags[gm], (unsigned)(t + 1),
                           __ATOMIC_RELAXED, __HIP_MEMORY_SCOPE_AGENT);
      // out stores off the critical path (retire under later waits)
#pragma unroll
      for (int r = 0; r < 4; ++r)
        __builtin_nontemporal_store(hv[r], out + ((size_t)(b0 + kg * 4 + r) * 256 + t) * 512 + m0 + ll);
      // parallel poll: tid 0..15 each watch one wg's flag (same 64B line)
      if (tid < 16) {
        unsigned guard = 0;
        while (__hip_atomic_load(&gflags[tid], __ATOMIC_RELAXED,
                                 __HIP_MEMORY_SCOPE_AGENT) <= (unsigned)t) {
          if (++guard > (1u << 15)) break; // valve: terminate, don't hang
          __builtin_amdgcn_s_sleep(1);
        }
      }
      __builtin_amdgcn_s_barrier();
    } else {
#pragma unroll
      for (int r = 0; r < 4; ++r)
        __builtin_nontemporal_store(hv[r], out + ((size_t)(b0 + kg * 4 + r) * 256 + t) * 512 + m0 + ll);
    }
  }
}

// ---------------------------------------------------------------------------
extern "C" void kernel_launch(void* const* d_in, const int* in_sizes, int n_in,
                              void* d_out, int out_size, void* d_ws, size_t ws_size,
                              hipStream_t stream)
{
  const float* inputs = (const float*)d_in[0];
  // d_in[1..3] = W_e_w, W_e_b, U_e_w : dead (softmax of constant row)
  const float* w_ih = (const float*)d_in[4];
  const float* w_hh = (const float*)d_in[5];
  const float* b_ih = (const float*)d_in[6];
  const float* b_hh = (const float*)d_in[7];
  float* out = (float*)d_out;
  char* ws = (char*)d_ws;

  const size_t xg_f32_bytes = (size_t)32768 * 2048 * 4;  // 268.4 MB
  const size_t xg_bf_bytes  = (size_t)32768 * 2048 * 2;  // 134.2 MB
  const size_t xbytes = (size_t)16777216 * 2;            // X bf16
  const size_t wbytes = (size_t)1048576 * 2;             // w_ih bf16
  const size_t biasb  = 2048 * 4;
  const size_t hbytes = (size_t)2 * 128 * 512 * 2;       // h double buffer
  const size_t flagb  = 256;                             // 4 groups x 16 flags
  const size_t tail = xbytes + wbytes + biasb + hbytes + flagb + 1024;

  bool f32p = ws_size >= xg_f32_bytes + tail;            // adaptive xg precision
  size_t xgb  = f32p ? xg_f32_bytes : xg_bf_bytes;
  size_t oX   = xgb;
  size_t oW   = oX + xbytes;
  size_t oB   = oW + wbytes;
  size_t oH   = (oB + biasb + 255) & ~(size_t)255;
  size_t oF   = oH + hbytes;

  hipMemsetAsync(ws + oH, 0, hbytes + flagb, stream);    // zero h0 + flags

  convert_kernel<<<2048, 256, 0, stream>>>(inputs, w_ih, b_ih, b_hh,
      (ushort_t*)(ws + oX), (ushort_t*)(ws + oW), (float*)(ws + oB));

  if (f32p) {
    gemm_xg_kernel<false><<<4096, 256, 0, stream>>>(
        (const ushort_t*)(ws + oX), (const ushort_t*)(ws + oW), (const float*)(ws + oB), ws);
    lstm_rec_kernel<false><<<64, 256, 0, stream>>>(
        w_hh, ws, (ushort_t*)(ws + oH), out, (unsigned*)(ws + oF));
  } else {
    gemm_xg_kernel<true><<<4096, 256, 0, stream>>>(
        (const ushort_t*)(ws + oX), (const ushort_t*)(ws + oW), (const float*)(ws + oB), ws);
    lstm_rec_kernel<true><<<64, 256, 0, stream>>>(
        w_hh, ws, (ushort_t*)(ws + oH), out, (unsigned*)(ws + oF));
  }
  (void)in_sizes; (void)n_in; (void)out_size;
}